// Round 14
// baseline (161.641 us; speedup 1.0000x reference)
//
#include <hip/hip_runtime.h>

#define NSAMP 2048
#define NCONF 128
#define NMO   64
#define NE    16   // electrons per spin (matrix dim)

// Block = 256 threads = 2 samples x 128 configs.
// LDS: samples staged TRANSPOSED (column-major per (sample,spin) plane) with
// XOR swizzle on the 16B slot: word(c,r)=c*16+(((r>>2)^h(c))<<2)|(r&3),
// h(c)=(c^(c>>2))&3. One matrix column = 4 x ds_read_b128.
//
// Per thread: det(up)*det(dn) via LEFT-LOOKING UNPIVOTED LU (Crout) --
// byte-identical math to the round-13 28us kernel.
// Column j: forward-substitute through L columns 0..j-1 (each L element read
// once), pivot = a[j], det *= pivot, L[j][i>j] = a[i]*rcp (Newton-refined).
//
// (256,2): the ONE untested lever. All prior (256,2) spills were QR with
// ~190-220 live floats; LU's live set is ~170 (L=120 + a=16 + cidx=16 +
// misc), the first variant meaningfully below the 256-reg cap. Tripwire:
// WRITE_SIZE >5MB => spill => revert to round-13 verbatim.
__global__ __launch_bounds__(256, 2)
void SlaterPooling_45543833207162_kernel(const float* __restrict__ x,
                                         const int*   __restrict__ cup,
                                         const int*   __restrict__ cdn,
                                         float*       __restrict__ out) {
  __shared__ float tile[4 * 64 * NE];   // 4 planes x 64 cols x 16 rows = 16 KB
  float4* tile4 = reinterpret_cast<float4*>(tile);

  // ---- stage 16 KB coalesced; write transposed + swizzled ----
  {
    const float4* src = reinterpret_cast<const float4*>(
        x + (size_t)blockIdx.x * 2 * (2 * NE * NMO));
#pragma unroll
    for (int k = 0; k < 4; ++k) {
      const int   f4 = threadIdx.x + k * 256;   // float4 index in block region
      const float4 v = src[f4];
      const int flat  = f4 * 4;                 // word index (row-major global)
      const int plane = flat >> 10;             // (s_local, spin) plane 0..3
      const int r     = (flat >> 6) & 15;       // row within plane
      const int c4    = (flat >> 2) & 15;       // c = 4*c4 + d
      const int rlo = r & 3, rhi = r >> 2;
      const float vv[4] = {v.x, v.y, v.z, v.w};
#pragma unroll
      for (int d = 0; d < 4; ++d) {
        const int cc = 4 * c4 + d;
        const int h  = (d ^ c4) & 3;            // == (cc ^ (cc>>2)) & 3
        tile[plane * 1024 + cc * NE + (((rhi ^ h) << 2) | rlo)] = vv[d];
      }
    }
  }
  __syncthreads();

  const int s_local = threadIdx.x >> 7;         // 0..1
  const int c       = threadIdx.x & 127;        // config index
  float result = 1.0f;

  // spin loop NOT unrolled: L and column regs reused across spins
#pragma unroll 1
  for (int spin = 0; spin < 2; ++spin) {
    // ---- config indices: 4 x int4, hoisted out of the column loop ----
    const int4* cfg4 = reinterpret_cast<const int4*>(
        (spin ? cdn : cup) + c * NE);
    const int4 q0 = cfg4[0], q1 = cfg4[1], q2 = cfg4[2], q3 = cfg4[3];
    const int cidx[16] = {q0.x, q0.y, q0.z, q0.w,  q1.x, q1.y, q1.z, q1.w,
                          q2.x, q2.y, q2.z, q2.w,  q3.x, q3.y, q3.z, q3.w};

    const float4* plane4 = tile4 + (s_local * 2 + spin) * 256;

    float L[NE - 1][NE];   // L column k lives in L[k][k+1..15]
    float det = 1.0f;      // no pivoting -> no sign correction

#pragma unroll
    for (int j = 0; j < NE; ++j) {
      // ---- column j: 4 x ds_read_b128 from the swizzled plane ----
      const int cj = cidx[j];
      const int h  = (cj ^ (cj >> 2)) & 3;
      const float4* col = plane4 + cj * 4;
      float a[NE];
      { const float4 t = col[0 ^ h]; a[ 0]=t.x; a[ 1]=t.y; a[ 2]=t.z; a[ 3]=t.w; }
      { const float4 t = col[1 ^ h]; a[ 4]=t.x; a[ 5]=t.y; a[ 6]=t.z; a[ 7]=t.w; }
      { const float4 t = col[2 ^ h]; a[ 8]=t.x; a[ 9]=t.y; a[10]=t.z; a[11]=t.w; }
      { const float4 t = col[3 ^ h]; a[12]=t.x; a[13]=t.y; a[14]=t.z; a[15]=t.w; }

      // ---- forward substitution through L columns 0..j-1 ----
      // (k<j folds at compile time; each L[k][i] read exactly once)
#pragma unroll
      for (int k = 0; k < NE - 1; ++k) {
        if (k < j) {
          const float uk = a[k];
#pragma unroll
          for (int i = k + 1; i < NE; ++i)
            a[i] = fmaf(-L[k][i], uk, a[i]);
        }
      }

      // ---- pivot, det update, form L column j ----
      const float p = a[j];
      det *= p;
      if (j < NE - 1) {
        float r = __builtin_amdgcn_rcpf(p);
        r = r * fmaf(-p, r, 2.0f);              // one Newton step: ~1 ulp
#pragma unroll
        for (int i = j + 1; i < NE; ++i)
          L[j][i] = a[i] * r;
      }
    }
    result *= det;
  }

  // out[s*128 + c]
  out[(blockIdx.x * 2 + s_local) * NCONF + c] = result;
}

extern "C" void kernel_launch(void* const* d_in, const int* in_sizes, int n_in,
                              void* d_out, int out_size, void* d_ws, size_t ws_size,
                              hipStream_t stream) {
  const float* x   = (const float*)d_in[0];
  const int*   cup = (const int*)d_in[1];
  const int*   cdn = (const int*)d_in[2];
  float*       out = (float*)d_out;

  dim3 grid(NSAMP / 2), block(256);   // 1024 blocks, 2 samples each
  hipLaunchKernelGGL(SlaterPooling_45543833207162_kernel, grid, block, 0, stream,
                     x, cup, cdn, out);
}

// Round 15
// 23.881 us; speedup vs baseline: 6.7686x; 6.7686x over previous
//
#include <hip/hip_runtime.h>

#define NSAMP 2048
#define NCONF 128
#define NMO   64
#define NE    16   // electrons per spin (matrix dim)

typedef float v2f __attribute__((ext_vector_type(2)));

// Block = 256 threads = 2 samples x 128 configs.
// LDS: samples staged TRANSPOSED (column-major per (sample,spin) plane) with
// XOR swizzle on the 16B slot: word(c,r)=c*16+(((r>>2)^h(c))<<2)|(r&3),
// h(c)=(c^(c>>2))&3. One matrix column = 4 x ds_read_b128.
// (Staging/gather/cidx/(256,1) byte-identical to the round-13 28us kernel.)
//
// Per thread: det(up)*det(dn) via LEFT-LOOKING UNPIVOTED LU (Crout),
// PACKED-FP32: column a and L rows held as float2 ext-vectors;
// __builtin_elementwise_fma lowers to v_pk_fma_f32 (2 FMA/instr, the
// reason gfx950 fp32 vector peak is 157 TF not 78.6). ~650 packed FMA/spin
// replaces ~1240 scalar FMA. Pair-boundary handling: full-pair updates
// everywhere; every slot corrupted by a full-pair FMA is dead (multiplier
// extracted beforehand), every dead slot holds a finite value (p*r~=1 or
// FMA chains of finite inputs) -> numerics identical to round 13 up to
// rounding order.
__global__ __launch_bounds__(256, 1)
void SlaterPooling_45543833207162_kernel(const float* __restrict__ x,
                                         const int*   __restrict__ cup,
                                         const int*   __restrict__ cdn,
                                         float*       __restrict__ out) {
  __shared__ float tile[4 * 64 * NE];   // 4 planes x 64 cols x 16 rows = 16 KB
  float4* tile4 = reinterpret_cast<float4*>(tile);

  // ---- stage 16 KB coalesced; write transposed + swizzled ----
  {
    const float4* src = reinterpret_cast<const float4*>(
        x + (size_t)blockIdx.x * 2 * (2 * NE * NMO));
#pragma unroll
    for (int k = 0; k < 4; ++k) {
      const int   f4 = threadIdx.x + k * 256;   // float4 index in block region
      const float4 v = src[f4];
      const int flat  = f4 * 4;                 // word index (row-major global)
      const int plane = flat >> 10;             // (s_local, spin) plane 0..3
      const int r     = (flat >> 6) & 15;       // row within plane
      const int c4    = (flat >> 2) & 15;       // c = 4*c4 + d
      const int rlo = r & 3, rhi = r >> 2;
      const float vv[4] = {v.x, v.y, v.z, v.w};
#pragma unroll
      for (int d = 0; d < 4; ++d) {
        const int cc = 4 * c4 + d;
        const int h  = (d ^ c4) & 3;            // == (cc ^ (cc>>2)) & 3
        tile[plane * 1024 + cc * NE + (((rhi ^ h) << 2) | rlo)] = vv[d];
      }
    }
  }
  __syncthreads();

  const int s_local = threadIdx.x >> 7;         // 0..1
  const int c       = threadIdx.x & 127;        // config index
  float result = 1.0f;

  // spin loop NOT unrolled: L2 and column regs reused across spins
#pragma unroll 1
  for (int spin = 0; spin < 2; ++spin) {
    // ---- config indices: 4 x int4, hoisted out of the column loop ----
    const int4* cfg4 = reinterpret_cast<const int4*>(
        (spin ? cdn : cup) + c * NE);
    const int4 q0 = cfg4[0], q1 = cfg4[1], q2 = cfg4[2], q3 = cfg4[3];
    const int cidx[16] = {q0.x, q0.y, q0.z, q0.w,  q1.x, q1.y, q1.z, q1.w,
                          q2.x, q2.y, q2.z, q2.w,  q3.x, q3.y, q3.z, q3.w};

    const float4* plane4 = tile4 + (s_local * 2 + spin) * 256;

    v2f L2[NE - 1][8];   // L column k lives in pairs m = k>>1 .. 7
    float det = 1.0f;    // no pivoting -> no sign correction

#pragma unroll
    for (int j = 0; j < NE; ++j) {
      // ---- column j: 4 x ds_read_b128 from the swizzled plane ----
      const int cj = cidx[j];
      const int h  = (cj ^ (cj >> 2)) & 3;
      const float4* col = plane4 + cj * 4;
      v2f a2[8];
      { const float4 t = col[0 ^ h]; a2[0] = v2f{t.x, t.y}; a2[1] = v2f{t.z, t.w}; }
      { const float4 t = col[1 ^ h]; a2[2] = v2f{t.x, t.y}; a2[3] = v2f{t.z, t.w}; }
      { const float4 t = col[2 ^ h]; a2[4] = v2f{t.x, t.y}; a2[5] = v2f{t.z, t.w}; }
      { const float4 t = col[3 ^ h]; a2[6] = v2f{t.x, t.y}; a2[7] = v2f{t.z, t.w}; }

      // ---- forward substitution through L columns 0..j-1 (packed) ----
      // (k<j folds at compile time; full-pair FMAs, dead slots harmless)
#pragma unroll
      for (int k = 0; k < NE - 1; ++k) {
        if (k < j) {
          const float uk = (k & 1) ? a2[k >> 1].y : a2[k >> 1].x;
          const v2f ukv = {uk, uk};
#pragma unroll
          for (int m = k >> 1; m < 8; ++m)
            a2[m] = __builtin_elementwise_fma(-L2[k][m], ukv, a2[m]);
        }
      }

      // ---- pivot, det update, form L column j (packed scale) ----
      const float p = (j & 1) ? a2[j >> 1].y : a2[j >> 1].x;
      det *= p;
      if (j < NE - 1) {
        float r = __builtin_amdgcn_rcpf(p);
        r = r * fmaf(-p, r, 2.0f);              // one Newton step: ~1 ulp
        const v2f rv = {r, r};
#pragma unroll
        for (int m = j >> 1; m < 8; ++m)
          L2[j][m] = a2[m] * rv;
      }
    }
    result *= det;
  }

  // out[s*128 + c]
  out[(blockIdx.x * 2 + s_local) * NCONF + c] = result;
}

extern "C" void kernel_launch(void* const* d_in, const int* in_sizes, int n_in,
                              void* d_out, int out_size, void* d_ws, size_t ws_size,
                              hipStream_t stream) {
  const float* x   = (const float*)d_in[0];
  const int*   cup = (const int*)d_in[1];
  const int*   cdn = (const int*)d_in[2];
  float*       out = (float*)d_out;

  dim3 grid(NSAMP / 2), block(256);   // 1024 blocks, 2 samples each
  hipLaunchKernelGGL(SlaterPooling_45543833207162_kernel, grid, block, 0, stream,
                     x, cup, cdn, out);
}